// Round 1
// baseline (2215.053 us; speedup 1.0000x reference)
//
#include <hip/hip_runtime.h>
#include <math.h>

// Problem dims
#define TB 16   // batch (tasks)
#define TT 16   // train steps
#define LL 128  // test length
#define XX 256  // x dim
#define HH 512  // hidden
#define YY 256  // y dim

__device__ __forceinline__ float wred(float v) {
    v += __shfl_xor(v, 32);
    v += __shfl_xor(v, 16);
    v += __shfl_xor(v, 8);
    v += __shfl_xor(v, 4);
    v += __shfl_xor(v, 2);
    v += __shfl_xor(v, 1);
    return v;
}

// ---------------------------------------------------------------------------
// Per-task 16-block barrier (sense-reversing, device-scope). All 256 blocks
// trivially co-resident: grid = 256 = #CUs, 256 thr, 28KB LDS.
// ---------------------------------------------------------------------------
__device__ __forceinline__ void gsync(unsigned* tb) {
    __syncthreads();
    if (threadIdx.x == 0) {
        __threadfence();
        unsigned gen = __hip_atomic_load(&tb[1], __ATOMIC_RELAXED, __HIP_MEMORY_SCOPE_AGENT);
        unsigned arrive = __hip_atomic_fetch_add(&tb[0], 1u, __ATOMIC_ACQ_REL, __HIP_MEMORY_SCOPE_AGENT);
        if (arrive == 15u) {
            __hip_atomic_store(&tb[0], 0u, __ATOMIC_RELAXED, __HIP_MEMORY_SCOPE_AGENT);
            __hip_atomic_store(&tb[1], gen + 1u, __ATOMIC_RELEASE, __HIP_MEMORY_SCOPE_AGENT);
        } else {
            while (__hip_atomic_load(&tb[1], __ATOMIC_ACQUIRE, __HIP_MEMORY_SCOPE_AGENT) == gen) {
                __builtin_amdgcn_s_sleep(2);
            }
        }
    }
    __syncthreads();
}

// ---------------------------------------------------------------------------
// Transpose W1..W4 (64x64 tiles), zero barrier flags, write inner_lr output.
// grid: 192 blocks of 256
// ---------------------------------------------------------------------------
__global__ __launch_bounds__(256) void k_tr(
    const float* __restrict__ W1, const float* __restrict__ W2,
    const float* __restrict__ W3, const float* __restrict__ W4,
    float* __restrict__ WT1, float* __restrict__ WT2,
    float* __restrict__ WT3, float* __restrict__ WT4,
    const float* __restrict__ loglr, float* __restrict__ out,
    unsigned* __restrict__ bars)
{
    const int tid = threadIdx.x;
    int bid = blockIdx.x;
    if (blockIdx.x == 0) bars[tid] = 0u;           // 256 uints
    if (blockIdx.x == 0 && tid == 0) out[2048] = expf(loglr[0]);

    const float* src; float* dst; int R, C;
    if (bid < 32)       { src = W1; dst = WT1; R = 512; C = 256; }
    else if (bid < 96)  { src = W2; dst = WT2; R = 512; C = 512; bid -= 32; }
    else if (bid < 160) { src = W3; dst = WT3; R = 512; C = 512; bid -= 96; }
    else                { src = W4; dst = WT4; R = 256; C = 512; bid -= 160; }
    const int tilesC = C >> 6;
    const int i0 = (bid / tilesC) * 64, j0 = (bid % tilesC) * 64;

    __shared__ float sm[64][65];
    #pragma unroll
    for (int rep = 0; rep < 16; ++rep) {
        const int flat = rep * 256 + tid;
        const int r = flat >> 6, c = flat & 63;
        sm[r][c] = src[(i0 + r) * C + j0 + c];
    }
    __syncthreads();
    #pragma unroll
    for (int rep = 0; rep < 16; ++rep) {
        const int flat = rep * 256 + tid;
        const int c = flat >> 6, r = flat & 63;
        dst[(j0 + c) * R + i0 + r] = sm[r][c];
    }
}

// ---------------------------------------------------------------------------
// Matvec helpers. Layout: column-access matrix M[K][OUTTOT] (i.e. transposed
// weights for forward, original weights for backward). Per block: 32 (or 16)
// output rows, k-split across thread groups, independent accumulation,
// 1 shuffle + 1 LDS hop reduce. Result valid for tid < 32 (resp. 16).
// ---------------------------------------------------------------------------
__device__ __forceinline__ float mv_h(const float* __restrict__ M, const float* sv,
                                      int baseRow, float* sp) {
    const int tid = threadIdx.x;
    const int r = tid & 31, j = tid >> 5;
    const float* col = M + (j * 64) * HH + baseRow + r;
    const float* vv = sv + j * 64;
    float a = 0.f;
    #pragma unroll
    for (int k = 0; k < 64; ++k) a += col[k * HH] * vv[k];
    a += __shfl_xor(a, 32);
    const int lane = tid & 63, w = tid >> 6;
    if (lane < 32) sp[w * 32 + lane] = a;
    __syncthreads();
    float s2 = 0.f;
    if (tid < 32) s2 = sp[tid] + sp[32 + tid] + sp[64 + tid] + sp[96 + tid];
    return s2;
}

__device__ __forceinline__ float mv_b4(const float* __restrict__ M, const float* sv,
                                       int baseRow, float* sp) {   // K=256 -> 512
    const int tid = threadIdx.x;
    const int r = tid & 31, j = tid >> 5;
    const float* col = M + (j * 32) * HH + baseRow + r;
    const float* vv = sv + j * 32;
    float a = 0.f;
    #pragma unroll
    for (int k = 0; k < 32; ++k) a += col[k * HH] * vv[k];
    a += __shfl_xor(a, 32);
    const int lane = tid & 63, w = tid >> 6;
    if (lane < 32) sp[w * 32 + lane] = a;
    __syncthreads();
    float s2 = 0.f;
    if (tid < 32) s2 = sp[tid] + sp[32 + tid] + sp[64 + tid] + sp[96 + tid];
    return s2;
}

__device__ __forceinline__ float mv_y(const float* __restrict__ M, const float* sv,
                                      int baseRow, float* sp) {    // K=512 -> 256
    const int tid = threadIdx.x;
    const int r = tid & 15, j = tid >> 4;
    const float* col = M + (j * 32) * YY + baseRow + r;
    const float* vv = sv + j * 32;
    float a = 0.f;
    #pragma unroll
    for (int k = 0; k < 32; ++k) a += col[k * YY] * vv[k];
    a += __shfl_xor(a, 16);
    a += __shfl_xor(a, 32);
    const int lane = tid & 63, w = tid >> 6;
    if (lane < 16) sp[w * 16 + lane] = a;
    __syncthreads();
    float s2 = 0.f;
    if (tid < 16) s2 = sp[tid] + sp[16 + tid] + sp[32 + tid] + sp[48 + tid];
    return s2;
}

// Sum the 16 per-block partials into s_c[s] = lr * (c[s] + plus1), s < count.
__device__ __forceinline__ void cload(const float* crd, int count, float plus1,
                                      float lr, float* s_c) {
    const int tid = threadIdx.x;
    if (tid < count) {
        const float4* cp = (const float4*)(crd + tid * 16);
        const float4 a0 = cp[0], a1 = cp[1], a2 = cp[2], a3 = cp[3];
        const float ssum = (((a0.x + a0.y) + (a0.z + a0.w)) + ((a1.x + a1.y) + (a1.z + a1.w)))
                         + (((a2.x + a2.y) + (a2.z + a2.w)) + ((a3.x + a3.y) + (a3.z + a3.w)));
        s_c[tid] = lr * (ssum + plus1);
    }
}

// Partial dots of the freshly produced slice (sout, 32-wide) against history
// rows s <= tmax. thread layout: s = tid>>4, i = tid&15, 2 elems each.
__device__ __forceinline__ void partials32(const float* hist, int base, int tmax,
                                           float* cpw, int blk, const float* sout) {
    const int tid = threadIdx.x;
    const int s2 = tid >> 4, i = tid & 15;
    float pp = 0.f;
    const bool act = (s2 <= tmax);
    if (act) {
        const float2 h = *(const float2*)&hist[s2 * HH + base + 2 * i];
        pp = h.x * sout[2 * i] + h.y * sout[2 * i + 1];
    }
    pp += __shfl_xor(pp, 1);
    pp += __shfl_xor(pp, 2);
    pp += __shfl_xor(pp, 4);
    pp += __shfl_xor(pp, 8);
    if (act && i == 0) cpw[s2 * 16 + blk] = pp;
}

__device__ __forceinline__ void partials16(const float* hist, int base, int tmax,
                                           float* cpw, int blk, const float* sout) {
    const int tid = threadIdx.x;
    const int s2 = tid >> 4, i = tid & 15;
    float pp = 0.f;
    const bool act = (s2 <= tmax);
    if (act) pp = hist[s2 * YY + base + i] * sout[i];
    pp += __shfl_xor(pp, 1);
    pp += __shfl_xor(pp, 2);
    pp += __shfl_xor(pp, 4);
    pp += __shfl_xor(pp, 8);
    if (act && i == 0) cpw[s2 * 16 + blk] = pp;
}

// ---------------------------------------------------------------------------
// Persistent inner loop. 16 blocks per task, per-task barriers between the 6
// stages of each of the 16 SGD steps (97 barriers/task total).
// Prologue: Z1base = W1@x + b1 (all t), G1 gram, H1[0]. Then per step:
// F2,F3,F4,B4,B3,B2(+h1_{t+1}). Rank-correction coefficients flow through
// ping-pong cpart partial-dot buffers produced by each stage's epilogue.
// grid: 256 blocks of 256
// ---------------------------------------------------------------------------
__global__ __launch_bounds__(256) void k_inner(
    const float* __restrict__ tx, const float* __restrict__ ty, const float* __restrict__ tg,
    const float* __restrict__ b1v, const float* __restrict__ b2v, const float* __restrict__ b3v,
    const float* __restrict__ W2, const float* __restrict__ W3, const float* __restrict__ W4,
    const float* __restrict__ WT1, const float* __restrict__ WT2, const float* __restrict__ WT3,
    const float* __restrict__ WT4, const float* __restrict__ loglr,
    float* __restrict__ Z1, float* __restrict__ G1,
    float* __restrict__ H1, float* __restrict__ H2, float* __restrict__ HG,
    float* __restrict__ D1, float* __restrict__ D2, float* __restrict__ D3, float* __restrict__ D4,
    float* __restrict__ cpart, unsigned* __restrict__ bars)
{
    const int tid = threadIdx.x;
    const int lane = tid & 63, w = tid >> 6;
    const int b = blockIdx.x >> 4, blk = blockIdx.x & 15;
    const int base = blk * 32, base16 = blk * 16;
    const float lr = expf(loglr[0]);
    unsigned* tb = bars + b * 16;

    const float* txb = tx + b * (TT * XX);
    const float* tyb = ty + b * (TT * YY);
    const float* tgb = tg + b * (TT * HH);
    float* Z1b = Z1 + b * (TT * HH);
    float* G1b = G1 + b * (TT * TT);
    float* H1b = H1 + b * (TT * HH);
    float* H2b = H2 + b * (TT * HH);
    float* HGb = HG + b * (TT * HH);
    float* D1b = D1 + b * (TT * HH);
    float* D2b = D2 + b * (TT * HH);
    float* D3b = D3 + b * (TT * HH);
    float* D4b = D4 + b * (TT * YY);
    float* cw  = cpart + b * 256;          // parity-0 partial buffer [16 s][16 blk]
    float* crd = cpart + 4096 + b * 256;   // parity-1

    __shared__ float s_x[16 * 260];  // x staged, padded rows (bank-safe)
    __shared__ float spz[2176];      // P0 reduce scratch [4][32][17]
    __shared__ float s_v[HH];
    __shared__ float sp[128];
    __shared__ float sout[32];
    __shared__ float s_c[16];
    __shared__ float s_g[16];

    // ---------------- P0: Z1base, G1, H1[0] ----------------
    {
        const float4* src = (const float4*)txb;   // 1024 float4
        #pragma unroll
        for (int q = 0; q < 4; ++q) {
            const int idx = q * 256 + tid;
            const int tt = idx >> 6, k4 = idx & 63;
            *(float4*)&s_x[tt * 260 + k4 * 4] = src[idx];
        }
    }
    __syncthreads();
    {
        const int r = tid & 31, j = tid >> 5;
        float acc[16];
        #pragma unroll
        for (int tt = 0; tt < 16; ++tt) acc[tt] = 0.f;
        const float* col = WT1 + (j * 32) * HH + base + r;
        #pragma unroll 4
        for (int kk = 0; kk < 32; ++kk) {
            const float wv = col[kk * HH];
            const int k = j * 32 + kk;
            #pragma unroll
            for (int tt = 0; tt < 16; ++tt) acc[tt] += wv * s_x[tt * 260 + k];
        }
        #pragma unroll
        for (int tt = 0; tt < 16; ++tt) {
            float a = acc[tt] + __shfl_xor(acc[tt], 32);
            if (lane < 32) spz[w * 544 + lane * 17 + tt] = a;
        }
        __syncthreads();
        const int rr = tid & 31, tp = tid >> 5;
        #pragma unroll
        for (int q = 0; q < 2; ++q) {
            const int tt = tp * 2 + q;
            const int row = base + rr;
            float v = spz[rr * 17 + tt] + spz[544 + rr * 17 + tt] +
                      spz[1088 + rr * 17 + tt] + spz[1632 + rr * 17 + tt];
            v += b1v[row];
            Z1b[tt * HH + row] = v;
            if (tt == 0) H1b[row] = fmaxf(v, 0.f);
        }
    }
    if (blk == 15) {   // Gram matrix G1[s][u] = x_s.x_u + 1
        const int ss = tid >> 4, uu = tid & 15;
        float a = 0.f;
        for (int k = 0; k < 256; ++k) a += s_x[ss * 260 + k] * s_x[uu * 260 + k];
        G1b[ss * 16 + uu] = a + 1.0f;
    }
    gsync(tb);

    // ---------------- 16 SGD steps x 6 stages ----------------
    for (int t = 0; t < TT; ++t) {
        // ===== F2: h2 = relu(W2@h1 + b2 - lr*sum D2[s]*(h1_s.h1_t+1)) =====
        cload(crd, t, 1.0f, lr, s_c);
        if (tid < 128) ((float4*)s_v)[tid] = ((const float4*)(H1b + t * HH))[tid];
        __syncthreads();
        {
            const float sres = mv_h(WT2, s_v, base, sp);
            if (tid < 32) {
                const int row = base + tid;
                float corr = 0.f;
                for (int s2 = 0; s2 < t; ++s2) corr += D2b[s2 * HH + row] * s_c[s2];
                float v = sres + b2v[row] - corr;
                v = fmaxf(v, 0.f);
                H2b[t * HH + row] = v;
                sout[tid] = v;
            }
        }
        __syncthreads();
        partials32(H2b, base, t - 1, cw, blk, sout);
        { float* tmp = cw; cw = crd; crd = tmp; }
        gsync(tb);

        // ===== F3: hg = relu(W3@h2 + b3 - corr) * gate_t =====
        cload(crd, t, 1.0f, lr, s_c);
        if (tid < 128) ((float4*)s_v)[tid] = ((const float4*)(H2b + t * HH))[tid];
        __syncthreads();
        {
            const float sres = mv_h(WT3, s_v, base, sp);
            if (tid < 32) {
                const int row = base + tid;
                float corr = 0.f;
                for (int s2 = 0; s2 < t; ++s2) corr += D3b[s2 * HH + row] * s_c[s2];
                float v = sres + b3v[row] - corr;
                v = fmaxf(v, 0.f) * tgb[t * HH + row];
                HGb[t * HH + row] = v;
                sout[tid] = v;
            }
        }
        __syncthreads();
        partials32(HGb, base, t - 1, cw, blk, sout);
        { float* tmp = cw; cw = crd; crd = tmp; }
        gsync(tb);

        // ===== F4: logit = W4@hg - corr ; dlg = (logit - y)*2/Y -> D4[t] =====
        cload(crd, t, 0.0f, lr, s_c);
        if (tid < 128) ((float4*)s_v)[tid] = ((const float4*)(HGb + t * HH))[tid];
        __syncthreads();
        {
            const float sres = mv_y(WT4, s_v, base16, sp);
            if (tid < 16) {
                const int row = base16 + tid;
                float corr = 0.f;
                for (int s2 = 0; s2 < t; ++s2) corr += D4b[s2 * YY + row] * s_c[s2];
                const float z = sres - corr;
                const float dlg = (z - tyb[t * YY + row]) * (2.0f / YY);
                D4b[t * YY + row] = dlg;
                sout[tid] = dlg;
            }
        }
        __syncthreads();
        partials16(D4b, base16, t - 1, cw, blk, sout);
        { float* tmp = cw; cw = crd; crd = tmp; }
        gsync(tb);

        // ===== B4: dz3 = (W4^T dlg - corr) * gate_t * (HG_t>0) -> D3[t] =====
        cload(crd, t, 0.0f, lr, s_c);
        if (tid < 64) ((float4*)s_v)[tid] = ((const float4*)(D4b + t * YY))[tid];
        __syncthreads();
        {
            const float sres = mv_b4(W4, s_v, base, sp);
            if (tid < 32) {
                const int row = base + tid;
                float corr = 0.f;
                for (int s2 = 0; s2 < t; ++s2) corr += HGb[s2 * HH + row] * s_c[s2];
                const float hgt = HGb[t * HH + row];
                const float v = (sres - corr) * tgb[t * HH + row] * ((hgt > 0.f) ? 1.f : 0.f);
                D3b[t * HH + row] = v;
                sout[tid] = v;
            }
        }
        __syncthreads();
        partials32(D3b, base, t - 1, cw, blk, sout);
        { float* tmp = cw; cw = crd; crd = tmp; }
        gsync(tb);

        // ===== B3: dz2 = (W3^T dz3 - corr) * (H2_t>0) -> D2[t] =====
        cload(crd, t, 0.0f, lr, s_c);
        if (tid < 128) ((float4*)s_v)[tid] = ((const float4*)(D3b + t * HH))[tid];
        __syncthreads();
        {
            const float sres = mv_h(W3, s_v, base, sp);
            if (tid < 32) {
                const int row = base + tid;
                float corr = 0.f;
                for (int s2 = 0; s2 < t; ++s2) corr += H2b[s2 * HH + row] * s_c[s2];
                const float m = (H2b[t * HH + row] > 0.f) ? 1.f : 0.f;
                const float v = (sres - corr) * m;
                D2b[t * HH + row] = v;
                sout[tid] = v;
            }
        }
        __syncthreads();
        partials32(D2b, base, t - 1, cw, blk, sout);
        { float* tmp = cw; cw = crd; crd = tmp; }
        gsync(tb);

        // ===== B2: dz1 -> D1[t]; h1_{t+1} = relu(Z1base_{t+1} - lr*sum D1[s]*g1[s][t+1]) =====
        cload(crd, t, 0.0f, lr, s_c);
        if (tid < 16 && (t + 1) < TT) s_g[tid] = G1b[tid * 16 + (t + 1)];
        if (tid < 128) ((float4*)s_v)[tid] = ((const float4*)(D2b + t * HH))[tid];
        __syncthreads();
        {
            const float sres = mv_h(W2, s_v, base, sp);
            if (tid < 32) {
                const int row = base + tid;
                float corr = 0.f;
                for (int s2 = 0; s2 < t; ++s2) corr += H1b[s2 * HH + row] * s_c[s2];
                const float m = (H1b[t * HH + row] > 0.f) ? 1.f : 0.f;
                const float dz = (sres - corr) * m;
                D1b[t * HH + row] = dz;
                if (t + 1 < TT) {
                    float cr = dz * s_g[t];
                    for (int s2 = 0; s2 < t; ++s2) cr += D1b[s2 * HH + row] * s_g[s2];
                    const float z = Z1b[(t + 1) * HH + row];
                    const float h1n = fmaxf(z - lr * cr, 0.f);
                    H1b[(t + 1) * HH + row] = h1n;
                    sout[tid] = h1n;
                }
            }
        }
        __syncthreads();
        partials32(H1b, base, (t + 1 < TT) ? t : -1, cw, blk, sout);
        { float* tmp = cw; cw = crd; crd = tmp; }
        gsync(tb);
    }
}

// ---------------------------------------------------------------------------
// Phase-2 inner products: ip[b][s][l] = A[b][s] . (act[b][l] *? tg[b][l]) (+1)
// grid: B*T blocks of 256
// ---------------------------------------------------------------------------
template <int K, bool PLUSONE, bool GATE>
__global__ __launch_bounds__(256) void k_ip(
    const float* __restrict__ A, const float* __restrict__ act,
    const float* __restrict__ tg, float* __restrict__ ip)
{
    const int b = blockIdx.x / TT, s = blockIdx.x % TT;
    const int tid = threadIdx.x, lane = tid & 63, w = tid >> 6;
    constexpr int E = K / 64;

    float ar[E];
    #pragma unroll
    for (int j = 0; j < E; j += 4) {
        const float4 v = *(const float4*)&A[(b * TT + s) * K + lane * E + j];
        ar[j] = v.x; ar[j + 1] = v.y; ar[j + 2] = v.z; ar[j + 3] = v.w;
    }
    for (int l0 = 0; l0 < 32; ++l0) {
        const int l = w * 32 + l0;
        float a = 0.0f;
        #pragma unroll
        for (int j = 0; j < E; j += 4) {
            const float4 v = *(const float4*)&act[((long)b * LL + l) * K + lane * E + j];
            float gx = 1.0f, gy = 1.0f, gz = 1.0f, gw = 1.0f;
            if constexpr (GATE) {
                const float4 g = *(const float4*)&tg[((long)b * LL + l) * K + lane * E + j];
                gx = g.x; gy = g.y; gz = g.z; gw = g.w;
            }
            a += v.x * gx * ar[j] + v.y * gy * ar[j + 1] +
                 v.z * gz * ar[j + 2] + v.w * gw * ar[j + 3];
        }
        a = wred(a);
        if (lane == 0) ip[(b * TT + s) * LL + l] = a + (PLUSONE ? 1.0f : 0.0f);
    }
}

// ---------------------------------------------------------------------------
// Phase-2 layer: out[b][l][n] = post( W@act + bias - lr*sum_s D[s][n]*ip[s][l] )
// tile: 64 n x 32 l per WG; thread computes 2n x 4l.
// grid: B*(OUT/64)*(L/32) blocks of 256
// ---------------------------------------------------------------------------
template <int K, int OUT, bool RELU, bool BIAS, bool GATEIN>
__global__ __launch_bounds__(256) void k_layer(
    const float* __restrict__ W, const float* __restrict__ bias,
    const float* __restrict__ act, const float* __restrict__ tg,
    const float* __restrict__ Dl, const float* __restrict__ ip,
    float* __restrict__ outp, const float* __restrict__ loglr)
{
    constexpr int NC = OUT / 64;
    const int blk = blockIdx.x;
    const int b = blk / (NC * 4);
    const int rem = blk % (NC * 4);
    const int nc = rem / 4, lc = rem % 4;
    const int base_n = nc * 64, base_l = lc * 32;
    const int tid = threadIdx.x;
    const int tn = tid & 31, tl = tid >> 5;  // tl in 0..7
    const float lr = expf(loglr[0]);

    __shared__ float lw[64][65];
    __shared__ float lx[32][65];
    __shared__ float sD[TT][64];
    __shared__ float sip[TT][32];

    #pragma unroll
    for (int rep = 0; rep < 4; ++rep) {
        const int flat = rep * 256 + tid;
        const int s = flat >> 6, n = flat & 63;
        sD[s][n] = Dl[(b * TT + s) * OUT + base_n + n];
    }
    #pragma unroll
    for (int rep = 0; rep < 2; ++rep) {
        const int flat = rep * 256 + tid;
        const int s = flat >> 5, l = flat & 31;
        sip[s][l] = ip[(b * TT + s) * LL + base_l + l];
    }

    float acc[2][4] = {};
    for (int kc = 0; kc < K; kc += 64) {
        __syncthreads();
        #pragma unroll
        for (int rep = 0; rep < 16; ++rep) {
            const int flat = rep * 256 + tid;
            const int i = flat >> 6, k = flat & 63;
            lw[i][k] = W[(base_n + i) * K + kc + k];
        }
        #pragma unroll
        for (int rep = 0; rep < 8; ++rep) {
            const int flat = rep * 256 + tid;
            const int l = flat >> 6, k = flat & 63;
            float v = act[((long)b * LL + base_l + l) * K + kc + k];
            if constexpr (GATEIN)
                v *= tg[((long)b * LL + base_l + l) * K + kc + k];
            lx[l][k] = v;
        }
        __syncthreads();
        #pragma unroll 4
        for (int k = 0; k < 64; ++k) {
            const float w0 = lw[tn][k], w1 = lw[tn + 32][k];
            const float x0 = lx[tl][k],      x1 = lx[tl + 8][k];
            const float x2 = lx[tl + 16][k], x3 = lx[tl + 24][k];
            acc[0][0] += w0 * x0; acc[0][1] += w0 * x1;
            acc[0][2] += w0 * x2; acc[0][3] += w0 * x3;
            acc[1][0] += w1 * x0; acc[1][1] += w1 * x1;
            acc[1][2] += w1 * x2; acc[1][3] += w1 * x3;
        }
    }

    #pragma unroll
    for (int i = 0; i < 2; ++i) {
        const int n = base_n + tn + i * 32;
        const float bv = BIAS ? bias[n] : 0.0f;
        #pragma unroll
        for (int j = 0; j < 4; ++j) {
            const int l = base_l + tl + j * 8;
            float corr = 0.0f;
            #pragma unroll
            for (int s = 0; s < TT; ++s)
                corr += sD[s][tn + i * 32] * sip[s][tl + j * 8];
            float v = acc[i][j] + bv - lr * corr;
            if constexpr (RELU) v = fmaxf(v, 0.0f);
            outp[((long)b * LL + l) * OUT + n] = v;
        }
    }
}

// ---------------------------------------------------------------------------
// Loss: per (b,l): mean_y (logit-ty)^2 -> loss and evaluation
// grid: B*L blocks of 64
// ---------------------------------------------------------------------------
__global__ __launch_bounds__(64) void k_loss(
    const float* __restrict__ logit, const float* __restrict__ tey,
    float* __restrict__ loss, float* __restrict__ evalo)
{
    const int idx = blockIdx.x;
    const int lane = threadIdx.x;
    float a = 0.0f;
    #pragma unroll
    for (int j = 0; j < 4; ++j) {
        const float d = logit[(long)idx * YY + lane * 4 + j] -
                        tey[(long)idx * YY + lane * 4 + j];
        a += d * d;
    }
    a = wred(a);
    if (lane == 0) {
        const float v = a * (1.0f / YY);
        loss[idx] = v;
        evalo[idx] = v;
    }
}

// ---------------------------------------------------------------------------
extern "C" void kernel_launch(void* const* d_in, const int* in_sizes, int n_in,
                              void* d_out, int out_size, void* d_ws, size_t ws_size,
                              hipStream_t stream)
{
    const float* tx    = (const float*)d_in[0];   // train_x  [B][T][X]
    const float* ty    = (const float*)d_in[1];   // train_y  [B][T][Y]
    const float* tex   = (const float*)d_in[2];   // test_x   [B][L][X]
    const float* tey   = (const float*)d_in[3];   // test_y   [B][L][Y]
    const float* tg    = (const float*)d_in[4];   // train_gate [B][T][H]
    const float* teg   = (const float*)d_in[5];   // test_gate  [B][L][H]
    const float* W1    = (const float*)d_in[6];
    const float* b1    = (const float*)d_in[7];
    const float* W2    = (const float*)d_in[8];
    const float* b2    = (const float*)d_in[9];
    const float* W3    = (const float*)d_in[10];
    const float* b3    = (const float*)d_in[11];
    const float* W4    = (const float*)d_in[12];
    const float* loglr = (const float*)d_in[13];

    float* out = (float*)d_out;
    float* ws  = (float*)d_ws;

    // workspace layout (floats)
    float* Z1base = ws;                 // 131072
    float* G1     = ws + 131072;        // 4096
    float* H1     = ws + 135168;        // 131072
    float* H2     = ws + 266240;        // 131072
    float* HG     = ws + 397312;        // 131072
    float* D1     = ws + 528384;        // 131072
    float* D2     = ws + 659456;        // 131072
    float* D3     = ws + 790528;        // 131072
    float* D4     = ws + 921600;        // 65536
    float* IP     = ws + 991232;        // 32768
    float* ActA   = ws + 1024000;       // 1048576 (phase-1: holds WT1..WT4)
    float* ActB   = ws + 2072576;       // 1048576
    float* WT1    = ActA;               // [256][512] = 131072
    float* WT2    = ActA + 131072;      // [512][512] = 262144
    float* WT3    = ActA + 393216;      // [512][512] = 262144
    float* WT4    = ActA + 655360;      // [512][256] = 131072
    float* cpart  = ws + 3121152;       // 2 x [16 tasks][16 s][16 blk] = 8192
    unsigned* bars = (unsigned*)(ws + 3129344);  // 16 tasks x 16 uints

    // Transpose weights (once per launch), zero barriers, emit inner_lr.
    k_tr<<<192, 256, 0, stream>>>(W1, W2, W3, W4, WT1, WT2, WT3, WT4, loglr, out, bars);

    // Entire 16-step MAML inner loop in one persistent kernel.
    k_inner<<<TB * 16, 256, 0, stream>>>(tx, ty, tg, b1, b2, b3, W2, W3, W4,
                                         WT1, WT2, WT3, WT4, loglr,
                                         Z1base, G1, H1, H2, HG, D1, D2, D3, D4,
                                         cpart, bars);

    // ---- Phase 2: test-set forward with final (rank-16-corrected) weights ----
    k_ip<XX, true, false><<<TB * TT, 256, 0, stream>>>(tx, tex, nullptr, IP);
    k_layer<XX, HH, true, true, false><<<TB * 8 * 4, 256, 0, stream>>>(
        W1, b1, tex, nullptr, D1, IP, ActA, loglr);

    k_ip<HH, true, false><<<TB * TT, 256, 0, stream>>>(H1, ActA, nullptr, IP);
    k_layer<HH, HH, true, true, false><<<TB * 8 * 4, 256, 0, stream>>>(
        W2, b2, ActA, nullptr, D2, IP, ActB, loglr);

    k_ip<HH, true, false><<<TB * TT, 256, 0, stream>>>(H2, ActB, nullptr, IP);
    k_layer<HH, HH, true, true, false><<<TB * 8 * 4, 256, 0, stream>>>(
        W3, b3, ActB, nullptr, D3, IP, ActA, loglr);

    k_ip<HH, false, true><<<TB * TT, 256, 0, stream>>>(HG, ActA, teg, IP);
    k_layer<HH, YY, false, false, true><<<TB * 4 * 4, 256, 0, stream>>>(
        W4, nullptr, ActA, teg, D4, IP, out + 4097, loglr);

    k_loss<<<TB * LL, 64, 0, stream>>>(out + 4097, tey, out, out + 2049);
}

// Round 2
// 775.500 us; speedup vs baseline: 2.8563x; 2.8563x over previous
//
#include <hip/hip_runtime.h>
#include <math.h>

// Problem dims
#define TB 16   // batch (tasks)
#define TT 16   // train steps
#define LL 128  // test length
#define XX 256  // x dim
#define HH 512  // hidden
#define YY 256  // y dim

__device__ __forceinline__ float wred(float v) {
    v += __shfl_xor(v, 32);
    v += __shfl_xor(v, 16);
    v += __shfl_xor(v, 8);
    v += __shfl_xor(v, 4);
    v += __shfl_xor(v, 2);
    v += __shfl_xor(v, 1);
    return v;
}

// ---------------------------------------------------------------------------
// Relaxed device-scope atomics: execute at the memory-side coherent point
// (IF cache) with NO cache-maintenance fences (no buffer_inv / buffer_wbl2).
// Used for ALL cross-block-communicated values.
// ---------------------------------------------------------------------------
__device__ __forceinline__ void ast(float* p, float v) {
    __hip_atomic_store(p, v, __ATOMIC_RELAXED, __HIP_MEMORY_SCOPE_AGENT);
}
__device__ __forceinline__ float ald(const float* p) {
    return __hip_atomic_load(p, __ATOMIC_RELAXED, __HIP_MEMORY_SCOPE_AGENT);
}

// ---------------------------------------------------------------------------
// Per-task 16-block barrier: monotonic arrival counter + monotonic release
// generation, both relaxed device-scope. __syncthreads() on entry drains
// vmcnt(0) for ALL waves of the block (HIP __syncthreads semantics), so every
// data store is globally visible before the arrive-add issues. No fences.
// ---------------------------------------------------------------------------
__device__ __forceinline__ void gsync(unsigned* tb) {
    __syncthreads();   // drains vmcnt for all waves -> data stores are at IF
    if (threadIdx.x == 0) {
        unsigned arrive = __hip_atomic_fetch_add(&tb[0], 1u, __ATOMIC_RELAXED,
                                                 __HIP_MEMORY_SCOPE_AGENT);
        const unsigned gen = arrive >> 4;
        if ((arrive & 15u) == 15u) {
            __hip_atomic_store(&tb[4], gen + 1u, __ATOMIC_RELAXED,
                               __HIP_MEMORY_SCOPE_AGENT);
        } else {
            while (__hip_atomic_load(&tb[4], __ATOMIC_RELAXED,
                                     __HIP_MEMORY_SCOPE_AGENT) <= gen) {
                __builtin_amdgcn_s_sleep(1);
            }
        }
    }
    __syncthreads();
}

// ---------------------------------------------------------------------------
// Transpose W1..W4 (64x64 tiles), zero barrier flags, write inner_lr output.
// grid: 192 blocks of 256
// ---------------------------------------------------------------------------
__global__ __launch_bounds__(256) void k_tr(
    const float* __restrict__ W1, const float* __restrict__ W2,
    const float* __restrict__ W3, const float* __restrict__ W4,
    float* __restrict__ WT1, float* __restrict__ WT2,
    float* __restrict__ WT3, float* __restrict__ WT4,
    const float* __restrict__ loglr, float* __restrict__ out,
    unsigned* __restrict__ bars)
{
    const int tid = threadIdx.x;
    int bid = blockIdx.x;
    if (blockIdx.x == 0)   // zero barrier flags AT the coherent point
        __hip_atomic_store(&bars[tid], 0u, __ATOMIC_RELAXED, __HIP_MEMORY_SCOPE_AGENT);
    if (blockIdx.x == 0 && tid == 0) out[2048] = expf(loglr[0]);

    const float* src; float* dst; int R, C;
    if (bid < 32)       { src = W1; dst = WT1; R = 512; C = 256; }
    else if (bid < 96)  { src = W2; dst = WT2; R = 512; C = 512; bid -= 32; }
    else if (bid < 160) { src = W3; dst = WT3; R = 512; C = 512; bid -= 96; }
    else                { src = W4; dst = WT4; R = 256; C = 512; bid -= 160; }
    const int tilesC = C >> 6;
    const int i0 = (bid / tilesC) * 64, j0 = (bid % tilesC) * 64;

    __shared__ float sm[64][65];
    #pragma unroll
    for (int rep = 0; rep < 16; ++rep) {
        const int flat = rep * 256 + tid;
        const int r = flat >> 6, c = flat & 63;
        sm[r][c] = src[(i0 + r) * C + j0 + c];
    }
    __syncthreads();
    #pragma unroll
    for (int rep = 0; rep < 16; ++rep) {
        const int flat = rep * 256 + tid;
        const int c = flat >> 6, r = flat & 63;
        dst[(j0 + c) * R + i0 + r] = sm[r][c];
    }
}

// ---------------------------------------------------------------------------
// Matvec helpers (block-local; LDS + shfl only).
// ---------------------------------------------------------------------------
__device__ __forceinline__ float mv_h(const float* __restrict__ M, const float* sv,
                                      int baseRow, float* sp) {
    const int tid = threadIdx.x;
    const int r = tid & 31, j = tid >> 5;
    const float* col = M + (j * 64) * HH + baseRow + r;
    const float* vv = sv + j * 64;
    float a = 0.f;
    #pragma unroll
    for (int k = 0; k < 64; ++k) a += col[k * HH] * vv[k];
    a += __shfl_xor(a, 32);
    const int lane = tid & 63, w = tid >> 6;
    if (lane < 32) sp[w * 32 + lane] = a;
    __syncthreads();
    float s2 = 0.f;
    if (tid < 32) s2 = sp[tid] + sp[32 + tid] + sp[64 + tid] + sp[96 + tid];
    return s2;
}

__device__ __forceinline__ float mv_b4(const float* __restrict__ M, const float* sv,
                                       int baseRow, float* sp) {   // K=256 -> 512
    const int tid = threadIdx.x;
    const int r = tid & 31, j = tid >> 5;
    const float* col = M + (j * 32) * HH + baseRow + r;
    const float* vv = sv + j * 32;
    float a = 0.f;
    #pragma unroll
    for (int k = 0; k < 32; ++k) a += col[k * HH] * vv[k];
    a += __shfl_xor(a, 32);
    const int lane = tid & 63, w = tid >> 6;
    if (lane < 32) sp[w * 32 + lane] = a;
    __syncthreads();
    float s2 = 0.f;
    if (tid < 32) s2 = sp[tid] + sp[32 + tid] + sp[64 + tid] + sp[96 + tid];
    return s2;
}

__device__ __forceinline__ float mv_y(const float* __restrict__ M, const float* sv,
                                      int baseRow, float* sp) {    // K=512 -> 256
    const int tid = threadIdx.x;
    const int r = tid & 15, j = tid >> 4;
    const float* col = M + (j * 32) * YY + baseRow + r;
    const float* vv = sv + j * 32;
    float a = 0.f;
    #pragma unroll
    for (int k = 0; k < 32; ++k) a += col[k * YY] * vv[k];
    a += __shfl_xor(a, 16);
    a += __shfl_xor(a, 32);
    const int lane = tid & 63, w = tid >> 6;
    if (lane < 16) sp[w * 16 + lane] = a;
    __syncthreads();
    float s2 = 0.f;
    if (tid < 16) s2 = sp[tid] + sp[16 + tid] + sp[32 + tid] + sp[48 + tid];
    return s2;
}

// Sum 16 per-block partials -> s_c[s] = lr * (c[s] + plus1) for all s.
// (Entries for s >= current t contain garbage; they are never read.)
__device__ __forceinline__ void cload(const float* crd, float plus1,
                                      float lr, float* s_c) {
    const int tid = threadIdx.x;
    const int s = tid >> 4, j = tid & 15;
    float v = ald(crd + s * 16 + j);
    v += __shfl_xor(v, 1);
    v += __shfl_xor(v, 2);
    v += __shfl_xor(v, 4);
    v += __shfl_xor(v, 8);
    if (j == 0) s_c[s] = lr * (v + plus1);
}

// Partial dots of the freshly produced slice (sout, 32-wide) against history
// rows s <= tmax (history slice is block-PRIVATE -> normal cached loads).
__device__ __forceinline__ void partials32(const float* hist, int base, int tmax,
                                           float* cpw, int blk, const float* sout) {
    const int tid = threadIdx.x;
    const int s2 = tid >> 4, i = tid & 15;
    float pp = 0.f;
    const bool act = (s2 <= tmax);
    if (act) {
        const float2 h = *(const float2*)&hist[s2 * HH + base + 2 * i];
        pp = h.x * sout[2 * i] + h.y * sout[2 * i + 1];
    }
    pp += __shfl_xor(pp, 1);
    pp += __shfl_xor(pp, 2);
    pp += __shfl_xor(pp, 4);
    pp += __shfl_xor(pp, 8);
    if (act && i == 0) ast(&cpw[s2 * 16 + blk], pp);
}

__device__ __forceinline__ void partials16(const float* hist, int base, int tmax,
                                           float* cpw, int blk, const float* sout) {
    const int tid = threadIdx.x;
    const int s2 = tid >> 4, i = tid & 15;
    float pp = 0.f;
    const bool act = (s2 <= tmax);
    if (act) pp = hist[s2 * YY + base + i] * sout[i];
    pp += __shfl_xor(pp, 1);
    pp += __shfl_xor(pp, 2);
    pp += __shfl_xor(pp, 4);
    pp += __shfl_xor(pp, 8);
    if (act && i == 0) ast(&cpw[s2 * 16 + blk], pp);
}

// ---------------------------------------------------------------------------
// Persistent inner loop. 16 blocks per task; 97 fence-free barriers per task.
// Cross-block data (fresh 512-vectors, cpart, G1) via relaxed device atomics;
// per-slice correction history is block-private (normal cached loads).
// Slice mapping: blk = ((g&7)<<1)|((g>>3)&1) so each XCD (heuristic g%8)
// touches only rows [64r,64r+64) of every weight matrix -> L2-resident.
// grid: 256 blocks of 256
// ---------------------------------------------------------------------------
__global__ __launch_bounds__(256) void k_inner(
    const float* __restrict__ tx, const float* __restrict__ ty, const float* __restrict__ tg,
    const float* __restrict__ b1v, const float* __restrict__ b2v, const float* __restrict__ b3v,
    const float* __restrict__ W2, const float* __restrict__ W3, const float* __restrict__ W4,
    const float* __restrict__ WT1, const float* __restrict__ WT2, const float* __restrict__ WT3,
    const float* __restrict__ WT4, const float* __restrict__ loglr,
    float* __restrict__ Z1, float* __restrict__ G1,
    float* __restrict__ H1, float* __restrict__ H2, float* __restrict__ HG,
    float* __restrict__ D1, float* __restrict__ D2, float* __restrict__ D3, float* __restrict__ D4,
    float* __restrict__ cpart, unsigned* __restrict__ bars)
{
    const int tid = threadIdx.x;
    const int lane = tid & 63, w = tid >> 6;
    const int g = blockIdx.x;
    const int b = g >> 4;
    const int blk = ((g & 7) << 1) | ((g >> 3) & 1);
    const int base = blk * 32, base16 = blk * 16;
    const float lr = expf(loglr[0]);
    unsigned* tb = bars + b * 16;

    const float* txb = tx + b * (TT * XX);
    const float* tyb = ty + b * (TT * YY);
    const float* tgb = tg + b * (TT * HH);
    float* Z1b = Z1 + b * (TT * HH);
    float* G1b = G1 + b * (TT * TT);
    float* H1b = H1 + b * (TT * HH);
    float* H2b = H2 + b * (TT * HH);
    float* HGb = HG + b * (TT * HH);
    float* D1b = D1 + b * (TT * HH);
    float* D2b = D2 + b * (TT * HH);
    float* D3b = D3 + b * (TT * HH);
    float* D4b = D4 + b * (TT * YY);
    float* cw  = cpart + b * 256;          // parity-0 partial buffer [16 s][16 blk]
    float* crd = cpart + 4096 + b * 256;   // parity-1

    __shared__ float s_x[16 * 260];  // x staged, padded rows (bank-safe)
    __shared__ float spz[2176];      // P0 reduce scratch [4][32][17]
    __shared__ float s_v[HH];
    __shared__ float sp[128];
    __shared__ float sout[32];
    __shared__ float s_c[16];
    __shared__ float s_g[16];

    // ---------------- P0: Z1base, G1, H1[0] ----------------
    {
        const float4* src = (const float4*)txb;   // 1024 float4
        #pragma unroll
        for (int q = 0; q < 4; ++q) {
            const int idx = q * 256 + tid;
            const int tt = idx >> 6, k4 = idx & 63;
            *(float4*)&s_x[tt * 260 + k4 * 4] = src[idx];
        }
    }
    __syncthreads();
    {
        const int r = tid & 31, j = tid >> 5;
        float acc[16];
        #pragma unroll
        for (int tt = 0; tt < 16; ++tt) acc[tt] = 0.f;
        const float* col = WT1 + (j * 32) * HH + base + r;
        #pragma unroll 4
        for (int kk = 0; kk < 32; ++kk) {
            const float wv = col[kk * HH];
            const int k = j * 32 + kk;
            #pragma unroll
            for (int tt = 0; tt < 16; ++tt) acc[tt] += wv * s_x[tt * 260 + k];
        }
        #pragma unroll
        for (int tt = 0; tt < 16; ++tt) {
            float a = acc[tt] + __shfl_xor(acc[tt], 32);
            if (lane < 32) spz[w * 544 + lane * 17 + tt] = a;
        }
        __syncthreads();
        const int rr = tid & 31, tp = tid >> 5;
        #pragma unroll
        for (int q = 0; q < 2; ++q) {
            const int tt = tp * 2 + q;
            const int row = base + rr;
            float v = spz[rr * 17 + tt] + spz[544 + rr * 17 + tt] +
                      spz[1088 + rr * 17 + tt] + spz[1632 + rr * 17 + tt];
            v += b1v[row];
            Z1b[tt * HH + row] = v;                    // block-private
            if (tt == 0) ast(&H1b[row], fmaxf(v, 0.f));  // cross-block
        }
    }
    if (blk == 15) {   // Gram matrix G1[s][u] = x_s.x_u + 1  (cross-block)
        const int ss = tid >> 4, uu = tid & 15;
        float a = 0.f;
        for (int k = 0; k < 256; ++k) a += s_x[ss * 260 + k] * s_x[uu * 260 + k];
        ast(&G1b[ss * 16 + uu], a + 1.0f);
    }
    gsync(tb);

    // ---------------- 16 SGD steps x 6 stages ----------------
    for (int t = 0; t < TT; ++t) {
        // ===== F2: h2 = relu(W2@h1 + b2 - lr*sum D2[s]*(h1_s.h1_t+1)) =====
        cload(crd, 1.0f, lr, s_c);
        s_v[tid]       = ald(H1b + t * HH + tid);
        s_v[tid + 256] = ald(H1b + t * HH + 256 + tid);
        __syncthreads();
        {
            const float sres = mv_h(WT2, s_v, base, sp);
            if (tid < 32) {
                const int row = base + tid;
                float corr = 0.f;
                for (int s2 = 0; s2 < t; ++s2) corr += D2b[s2 * HH + row] * s_c[s2];
                float v = sres + b2v[row] - corr;
                v = fmaxf(v, 0.f);
                ast(&H2b[t * HH + row], v);
                sout[tid] = v;
            }
        }
        __syncthreads();
        partials32(H2b, base, t - 1, cw, blk, sout);
        { float* tmp = cw; cw = crd; crd = tmp; }
        gsync(tb);

        // ===== F3: hg = relu(W3@h2 + b3 - corr) * gate_t =====
        cload(crd, 1.0f, lr, s_c);
        s_v[tid]       = ald(H2b + t * HH + tid);
        s_v[tid + 256] = ald(H2b + t * HH + 256 + tid);
        __syncthreads();
        {
            const float sres = mv_h(WT3, s_v, base, sp);
            if (tid < 32) {
                const int row = base + tid;
                float corr = 0.f;
                for (int s2 = 0; s2 < t; ++s2) corr += D3b[s2 * HH + row] * s_c[s2];
                float v = sres + b3v[row] - corr;
                v = fmaxf(v, 0.f) * tgb[t * HH + row];
                ast(&HGb[t * HH + row], v);
                sout[tid] = v;
            }
        }
        __syncthreads();
        partials32(HGb, base, t - 1, cw, blk, sout);
        { float* tmp = cw; cw = crd; crd = tmp; }
        gsync(tb);

        // ===== F4: logit = W4@hg - corr ; dlg = (logit - y)*2/Y -> D4[t] =====
        cload(crd, 0.0f, lr, s_c);
        s_v[tid]       = ald(HGb + t * HH + tid);
        s_v[tid + 256] = ald(HGb + t * HH + 256 + tid);
        __syncthreads();
        {
            const float sres = mv_y(WT4, s_v, base16, sp);
            if (tid < 16) {
                const int row = base16 + tid;
                float corr = 0.f;
                for (int s2 = 0; s2 < t; ++s2) corr += D4b[s2 * YY + row] * s_c[s2];
                const float z = sres - corr;
                const float dlg = (z - tyb[t * YY + row]) * (2.0f / YY);
                ast(&D4b[t * YY + row], dlg);
                sout[tid] = dlg;
            }
        }
        __syncthreads();
        partials16(D4b, base16, t - 1, cw, blk, sout);
        { float* tmp = cw; cw = crd; crd = tmp; }
        gsync(tb);

        // ===== B4: dz3 = (W4^T dlg - corr) * gate_t * (HG_t>0) -> D3[t] =====
        cload(crd, 0.0f, lr, s_c);
        s_v[tid] = ald(D4b + t * YY + tid);
        __syncthreads();
        {
            const float sres = mv_b4(W4, s_v, base, sp);
            if (tid < 32) {
                const int row = base + tid;
                float corr = 0.f;
                for (int s2 = 0; s2 < t; ++s2) corr += HGb[s2 * HH + row] * s_c[s2];
                const float hgt = HGb[t * HH + row];
                const float v = (sres - corr) * tgb[t * HH + row] * ((hgt > 0.f) ? 1.f : 0.f);
                ast(&D3b[t * HH + row], v);
                sout[tid] = v;
            }
        }
        __syncthreads();
        partials32(D3b, base, t - 1, cw, blk, sout);
        { float* tmp = cw; cw = crd; crd = tmp; }
        gsync(tb);

        // ===== B3: dz2 = (W3^T dz3 - corr) * (H2_t>0) -> D2[t] =====
        cload(crd, 0.0f, lr, s_c);
        s_v[tid]       = ald(D3b + t * HH + tid);
        s_v[tid + 256] = ald(D3b + t * HH + 256 + tid);
        __syncthreads();
        {
            const float sres = mv_h(W3, s_v, base, sp);
            if (tid < 32) {
                const int row = base + tid;
                float corr = 0.f;
                for (int s2 = 0; s2 < t; ++s2) corr += H2b[s2 * HH + row] * s_c[s2];
                const float m = (H2b[t * HH + row] > 0.f) ? 1.f : 0.f;
                const float v = (sres - corr) * m;
                ast(&D2b[t * HH + row], v);
                sout[tid] = v;
            }
        }
        __syncthreads();
        partials32(D2b, base, t - 1, cw, blk, sout);
        { float* tmp = cw; cw = crd; crd = tmp; }
        gsync(tb);

        // ===== B2: dz1 -> D1[t]; h1_{t+1} = relu(Z1base_{t+1} - lr*sum D1[s]*g1[s][t+1]) =====
        cload(crd, 0.0f, lr, s_c);
        if (tid < 16 && (t + 1) < TT) s_g[tid] = ald(&G1b[tid * 16 + (t + 1)]);
        s_v[tid]       = ald(D2b + t * HH + tid);
        s_v[tid + 256] = ald(D2b + t * HH + 256 + tid);
        __syncthreads();
        {
            const float sres = mv_h(W2, s_v, base, sp);
            if (tid < 32) {
                const int row = base + tid;
                float corr = 0.f;
                for (int s2 = 0; s2 < t; ++s2) corr += H1b[s2 * HH + row] * s_c[s2];
                const float m = (H1b[t * HH + row] > 0.f) ? 1.f : 0.f;
                const float dz = (sres - corr) * m;
                ast(&D1b[t * HH + row], dz);
                if (t + 1 < TT) {
                    float cr = dz * s_g[t];
                    for (int s2 = 0; s2 < t; ++s2) cr += D1b[s2 * HH + row] * s_g[s2];
                    const float z = Z1b[(t + 1) * HH + row];
                    const float h1n = fmaxf(z - lr * cr, 0.f);
                    ast(&H1b[(t + 1) * HH + row], h1n);
                    sout[tid] = h1n;
                }
            }
        }
        __syncthreads();
        partials32(H1b, base, (t + 1 < TT) ? t : -1, cw, blk, sout);
        { float* tmp = cw; cw = crd; crd = tmp; }
        gsync(tb);
    }
}

// ---------------------------------------------------------------------------
// Phase-2 inner products: ip[b][s][l] = A[b][s] . (act[b][l] *? tg[b][l]) (+1)
// grid: B*T blocks of 256
// ---------------------------------------------------------------------------
template <int K, bool PLUSONE, bool GATE>
__global__ __launch_bounds__(256) void k_ip(
    const float* __restrict__ A, const float* __restrict__ act,
    const float* __restrict__ tg, float* __restrict__ ip)
{
    const int b = blockIdx.x / TT, s = blockIdx.x % TT;
    const int tid = threadIdx.x, lane = tid & 63, w = tid >> 6;
    constexpr int E = K / 64;

    float ar[E];
    #pragma unroll
    for (int j = 0; j < E; j += 4) {
        const float4 v = *(const float4*)&A[(b * TT + s) * K + lane * E + j];
        ar[j] = v.x; ar[j + 1] = v.y; ar[j + 2] = v.z; ar[j + 3] = v.w;
    }
    for (int l0 = 0; l0 < 32; ++l0) {
        const int l = w * 32 + l0;
        float a = 0.0f;
        #pragma unroll
        for (int j = 0; j < E; j += 4) {
            const float4 v = *(const float4*)&act[((long)b * LL + l) * K + lane * E + j];
            float gx = 1.0f, gy = 1.0f, gz = 1.0f, gw = 1.0f;
            if constexpr (GATE) {
                const float4 g = *(const float4*)&tg[((long)b * LL + l) * K + lane * E + j];
                gx = g.x; gy = g.y; gz = g.z; gw = g.w;
            }
            a += v.x * gx * ar[j] + v.y * gy * ar[j + 1] +
                 v.z * gz * ar[j + 2] + v.w * gw * ar[j + 3];
        }
        a = wred(a);
        if (lane == 0) ip[(b * TT + s) * LL + l] = a + (PLUSONE ? 1.0f : 0.0f);
    }
}

// ---------------------------------------------------------------------------
// Phase-2 layer: out[b][l][n] = post( W@act + bias - lr*sum_s D[s][n]*ip[s][l] )
// tile: 64 n x 32 l per WG; thread computes 2n x 4l.
// grid: B*(OUT/64)*(L/32) blocks of 256
// ---------------------------------------------------------------------------
template <int K, int OUT, bool RELU, bool BIAS, bool GATEIN>
__global__ __launch_bounds__(256) void k_layer(
    const float* __restrict__ W, const float* __restrict__ bias,
    const float* __restrict__ act, const float* __restrict__ tg,
    const float* __restrict__ Dl, const float* __restrict__ ip,
    float* __restrict__ outp, const float* __restrict__ loglr)
{
    constexpr int NC = OUT / 64;
    const int blk = blockIdx.x;
    const int b = blk / (NC * 4);
    const int rem = blk % (NC * 4);
    const int nc = rem / 4, lc = rem % 4;
    const int base_n = nc * 64, base_l = lc * 32;
    const int tid = threadIdx.x;
    const int tn = tid & 31, tl = tid >> 5;  // tl in 0..7
    const float lr = expf(loglr[0]);

    __shared__ float lw[64][65];
    __shared__ float lx[32][65];
    __shared__ float sD[TT][64];
    __shared__ float sip[TT][32];

    #pragma unroll
    for (int rep = 0; rep < 4; ++rep) {
        const int flat = rep * 256 + tid;
        const int s = flat >> 6, n = flat & 63;
        sD[s][n] = Dl[(b * TT + s) * OUT + base_n + n];
    }
    #pragma unroll
    for (int rep = 0; rep < 2; ++rep) {
        const int flat = rep * 256 + tid;
        const int s = flat >> 5, l = flat & 31;
        sip[s][l] = ip[(b * TT + s) * LL + base_l + l];
    }

    float acc[2][4] = {};
    for (int kc = 0; kc < K; kc += 64) {
        __syncthreads();
        #pragma unroll
        for (int rep = 0; rep < 16; ++rep) {
            const int flat = rep * 256 + tid;
            const int i = flat >> 6, k = flat & 63;
            lw[i][k] = W[(base_n + i) * K + kc + k];
        }
        #pragma unroll
        for (int rep = 0; rep < 8; ++rep) {
            const int flat = rep * 256 + tid;
            const int l = flat >> 6, k = flat & 63;
            float v = act[((long)b * LL + base_l + l) * K + kc + k];
            if constexpr (GATEIN)
                v *= tg[((long)b * LL + base_l + l) * K + kc + k];
            lx[l][k] = v;
        }
        __syncthreads();
        #pragma unroll 4
        for (int k = 0; k < 64; ++k) {
            const float w0 = lw[tn][k], w1 = lw[tn + 32][k];
            const float x0 = lx[tl][k],      x1 = lx[tl + 8][k];
            const float x2 = lx[tl + 16][k], x3 = lx[tl + 24][k];
            acc[0][0] += w0 * x0; acc[0][1] += w0 * x1;
            acc[0][2] += w0 * x2; acc[0][3] += w0 * x3;
            acc[1][0] += w1 * x0; acc[1][1] += w1 * x1;
            acc[1][2] += w1 * x2; acc[1][3] += w1 * x3;
        }
    }

    #pragma unroll
    for (int i = 0; i < 2; ++i) {
        const int n = base_n + tn + i * 32;
        const float bv = BIAS ? bias[n] : 0.0f;
        #pragma unroll
        for (int j = 0; j < 4; ++j) {
            const int l = base_l + tl + j * 8;
            float corr = 0.0f;
            #pragma unroll
            for (int s = 0; s < TT; ++s)
                corr += sD[s][tn + i * 32] * sip[s][tl + j * 8];
            float v = acc[i][j] + bv - lr * corr;
            if constexpr (RELU) v = fmaxf(v, 0.0f);
            outp[((long)b * LL + l) * OUT + n] = v;
        }
    }
}

// ---------------------------------------------------------------------------
// Loss: per (b,l): mean_y (logit-ty)^2 -> loss and evaluation
// grid: B*L blocks of 64
// ---------------------------------------------------------------------------
__global__ __launch_bounds__(64) void k_loss(
    const float* __restrict__ logit, const float* __restrict__ tey,
    float* __restrict__ loss, float* __restrict__ evalo)
{
    const int idx = blockIdx.x;
    const int lane = threadIdx.x;
    float a = 0.0f;
    #pragma unroll
    for (int j = 0; j < 4; ++j) {
        const float d = logit[(long)idx * YY + lane * 4 + j] -
                        tey[(long)idx * YY + lane * 4 + j];
        a += d * d;
    }
    a = wred(a);
    if (lane == 0) {
        const float v = a * (1.0f / YY);
        loss[idx] = v;
        evalo[idx] = v;
    }
}

// ---------------------------------------------------------------------------
extern "C" void kernel_launch(void* const* d_in, const int* in_sizes, int n_in,
                              void* d_out, int out_size, void* d_ws, size_t ws_size,
                              hipStream_t stream)
{
    const float* tx    = (const float*)d_in[0];   // train_x  [B][T][X]
    const float* ty    = (const float*)d_in[1];   // train_y  [B][T][Y]
    const float* tex   = (const float*)d_in[2];   // test_x   [B][L][X]
    const float* tey   = (const float*)d_in[3];   // test_y   [B][L][Y]
    const float* tg    = (const float*)d_in[4];   // train_gate [B][T][H]
    const float* teg   = (const float*)d_in[5];   // test_gate  [B][L][H]
    const float* W1    = (const float*)d_in[6];
    const float* b1    = (const float*)d_in[7];
    const float* W2    = (const float*)d_in[8];
    const float* b2    = (const float*)d_in[9];
    const float* W3    = (const float*)d_in[10];
    const float* b3    = (const float*)d_in[11];
    const float* W4    = (const float*)d_in[12];
    const float* loglr = (const float*)d_in[13];

    float* out = (float*)d_out;
    float* ws  = (float*)d_ws;

    // workspace layout (floats)
    float* Z1base = ws;                 // 131072
    float* G1     = ws + 131072;        // 4096
    float* H1     = ws + 135168;        // 131072
    float* H2     = ws + 266240;        // 131072
    float* HG     = ws + 397312;        // 131072
    float* D1     = ws + 528384;        // 131072
    float* D2     = ws + 659456;        // 131072
    float* D3     = ws + 790528;        // 131072
    float* D4     = ws + 921600;        // 65536
    float* IP     = ws + 991232;        // 32768
    float* ActA   = ws + 1024000;       // 1048576 (phase-1: holds WT1..WT4)
    float* ActB   = ws + 2072576;       // 1048576
    float* WT1    = ActA;               // [256][512] = 131072
    float* WT2    = ActA + 131072;      // [512][512] = 262144
    float* WT3    = ActA + 393216;      // [512][512] = 262144
    float* WT4    = ActA + 655360;      // [512][256] = 131072
    float* cpart  = ws + 3121152;       // 2 x [16 tasks][16 s][16 blk] = 8192
    unsigned* bars = (unsigned*)(ws + 3129344);  // 16 tasks x 16 uints

    // Transpose weights (once per launch), zero barriers, emit inner_lr.
    k_tr<<<192, 256, 0, stream>>>(W1, W2, W3, W4, WT1, WT2, WT3, WT4, loglr, out, bars);

    // Entire 16-step MAML inner loop in one persistent kernel.
    k_inner<<<TB * 16, 256, 0, stream>>>(tx, ty, tg, b1, b2, b3, W2, W3, W4,
                                         WT1, WT2, WT3, WT4, loglr,
                                         Z1base, G1, H1, H2, HG, D1, D2, D3, D4,
                                         cpart, bars);

    // ---- Phase 2: test-set forward with final (rank-16-corrected) weights ----
    k_ip<XX, true, false><<<TB * TT, 256, 0, stream>>>(tx, tex, nullptr, IP);
    k_layer<XX, HH, true, true, false><<<TB * 8 * 4, 256, 0, stream>>>(
        W1, b1, tex, nullptr, D1, IP, ActA, loglr);

    k_ip<HH, true, false><<<TB * TT, 256, 0, stream>>>(H1, ActA, nullptr, IP);
    k_layer<HH, HH, true, true, false><<<TB * 8 * 4, 256, 0, stream>>>(
        W2, b2, ActA, nullptr, D2, IP, ActB, loglr);

    k_ip<HH, true, false><<<TB * TT, 256, 0, stream>>>(H2, ActB, nullptr, IP);
    k_layer<HH, HH, true, true, false><<<TB * 8 * 4, 256, 0, stream>>>(
        W3, b3, ActB, nullptr, D3, IP, ActA, loglr);

    k_ip<HH, false, true><<<TB * TT, 256, 0, stream>>>(HG, ActA, teg, IP);
    k_layer<HH, YY, false, false, true><<<TB * 4 * 4, 256, 0, stream>>>(
        W4, nullptr, ActA, teg, D4, IP, out + 4097, loglr);

    k_loss<<<TB * LL, 64, 0, stream>>>(out + 4097, tey, out, out + 2049);
}